// Round 10
// baseline (198.157 us; speedup 1.0000x reference)
//
#include <hip/hip_runtime.h>
#include <math.h>

#define NF 32
#define NN 4096
#define ND 64
#define NK 512

// loss = q_latent + 0.25 * e_latent = 1.25 * mean((q - x)^2)
#define LOSS_SCALE (1.25f / (float)(NF * NN * ND))
// rescue margin: rows with approx top-2 gap < TAU get exact fp32 re-argmin.
#define TAU 6e-4f

#define NPARTIAL (NF * NN * 4 / 256)   // 2048 gather blocks

typedef short bf16x8 __attribute__((ext_vector_type(8)));
typedef float f32x4 __attribute__((ext_vector_type(4)));

static __device__ __forceinline__ unsigned short f2bf_rne(float f) {
    unsigned int u = __float_as_uint(f);
    u += 0x7FFFu + ((u >> 16) & 1u);
    return (unsigned short)(u >> 16);
}
static __device__ __forceinline__ float bf2f(unsigned short h) {
    return __uint_as_float(((unsigned int)h) << 16);
}

// ---------------------------------------------------------------------------
// prep_w (fused): wt[f][k][d] = w[f][d][k]; wh/wl bf16 split; w2h = 0.5||w||^2
// via 8-lane shuffle reduce. thread per (f,k,dc): 512 blocks.
// ---------------------------------------------------------------------------
__global__ __launch_bounds__(256)
void vq_prep_w(const float* __restrict__ w, float* __restrict__ wt,
               unsigned short* __restrict__ wh, unsigned short* __restrict__ wl,
               float* __restrict__ w2h) {
    const int gid = blockIdx.x * 256 + threadIdx.x;   // [0, NF*NK*8)
    const int dc = gid & 7;
    const int k  = (gid >> 3) & (NK - 1);
    const int f  = gid >> 12;
    const float* __restrict__ wf = w + (size_t)f * ND * NK;
    const size_t rowo = ((size_t)f * NK + k) * ND + dc * 8;

    float v[8];
    unsigned short hh[8], ll[8];
    float s = 0.0f;
#pragma unroll
    for (int j = 0; j < 8; ++j) {
        v[j] = wf[(dc * 8 + j) * NK + k];
        s = fmaf(v[j], v[j], s);
        hh[j] = f2bf_rne(v[j]);
        ll[j] = f2bf_rne(v[j] - bf2f(hh[j]));
    }
    *(float4*)(wt + rowo)     = make_float4(v[0], v[1], v[2], v[3]);
    *(float4*)(wt + rowo + 4) = make_float4(v[4], v[5], v[6], v[7]);
    *(ushort4*)(wh + rowo)     = make_ushort4(hh[0], hh[1], hh[2], hh[3]);
    *(ushort4*)(wh + rowo + 4) = make_ushort4(hh[4], hh[5], hh[6], hh[7]);
    *(ushort4*)(wl + rowo)     = make_ushort4(ll[0], ll[1], ll[2], ll[3]);
    *(ushort4*)(wl + rowo + 4) = make_ushort4(ll[4], ll[5], ll[6], ll[7]);

    s += __shfl_xor(s, 1, 64);
    s += __shfl_xor(s, 2, 64);
    s += __shfl_xor(s, 4, 64);
    if (dc == 0) w2h[f * NK + k] = 0.5f * s;
}

// ---------------------------------------------------------------------------
// argmin: block = 4 waves x SAME 64 rows; each wave owns a PRIVATE 128-col
// quarter. B-frags loaded DIRECTLY global->VGPR in MFMA frag layout (lane-
// linear 16B; the 4 loads/tile fully consume 16 cachelines). NO LDS staging,
// NO K-loop barriers -> compiler pipelines loads across tiles, waves drift
// freely. One barrier at the final cross-wave top-2 merge (3KB LDS).
// acc init = -0.5||w_k||^2, MFMA accumulates +x.w (3 split terms) -> sc=-c.
// XCD swizzle: 64 blocks per f all on one XCD (B quarter stays L2-hot).
// (256,2): 256-VGPR budget -> top-2 state stays in VGPRs (no AGPR thrash).
// grid: 2048 blocks = 8 blocks/CU (VGPR-capped ~3/CU resident).
// ---------------------------------------------------------------------------
__global__ __launch_bounds__(256, 2)
void vq_argmin(const float* __restrict__ x_in,
               const unsigned short* __restrict__ wh,
               const unsigned short* __restrict__ wl,
               const float* __restrict__ w2h,
               unsigned int* __restrict__ keys,
               unsigned char* __restrict__ flags) {
    const int b    = blockIdx.x;          // [0, 2048)
    const int xcd  = b & 7;
    const int j    = b >> 3;              // [0, 256)
    const int f    = xcd * 4 + (j & 3);
    const int n0   = (j >> 2) * 64;       // block's 64 rows
    const int tid  = threadIdx.x;
    const int wave = tid >> 6;            // col quarter owner
    const int lane = tid & 63;
    const int lc   = lane & 15;
    const int kq   = lane >> 4;

    __shared__ float nw2s[NK];                      // 2 KB (negated half-norms)
    __shared__ float mrg1[4][64], mrg2[4][64];      // cross-wave merge: 3 KB
    __shared__ int   mrgi[4][64];

    for (int t = tid; t < NK; t += 256) nw2s[t] = -w2h[f * NK + t];

    // ---- A-frags: the block's 64 rows (same for all 4 waves), split hi/lo.
    // A[m = lane&15][k = kq*8 + j]; mt selects rows n0 + mt*16 + lc.
    bf16x8 ah[4][2], al[4][2];
    const float* __restrict__ xbase = x_in + ((size_t)f * NN + n0 + lc) * ND;
#pragma unroll
    for (int mt = 0; mt < 4; ++mt) {
#pragma unroll
        for (int s = 0; s < 2; ++s) {
            const float* p = xbase + mt * 16 * ND + s * 32 + kq * 8;
            float4 u0 = *(const float4*)(p);
            float4 u1 = *(const float4*)(p + 4);
            float xv[8] = {u0.x, u0.y, u0.z, u0.w, u1.x, u1.y, u1.z, u1.w};
            bf16x8 h, l;
#pragma unroll
            for (int jj = 0; jj < 8; ++jj) {
                unsigned short hb = f2bf_rne(xv[jj]);
                unsigned short lb = f2bf_rne(xv[jj] - bf2f(hb));
                h[jj] = (short)hb;
                l[jj] = (short)lb;
            }
            ah[mt][s] = h;
            al[mt][s] = l;
        }
    }

    const unsigned short* __restrict__ whf = wh + (size_t)f * NK * ND;
    const unsigned short* __restrict__ wlf = wl + (size_t)f * NK * ND;
    const int cq = wave * 128;            // this wave's column quarter

    float m1[16], m2[16];
    int idx[16];
#pragma unroll
    for (int ri = 0; ri < 16; ++ri) { m1[ri] = INFINITY; m2[ri] = INFINITY; idx[ri] = 0; }

    __syncthreads();                      // nw2s ready

#pragma unroll 2
    for (int tl = 0; tl < 8; ++tl) {
        const int colbase = cq + tl * 16;
        const int col = colbase + lc;
        // B-frags straight from global in frag layout:
        // element (colbase+lc)*ND + kq*8 (+32 for kstep 1)
        const size_t bo = (size_t)col * ND + kq * 8;
        bf16x8 bh0 = *(const bf16x8*)(whf + bo);
        bf16x8 bh1 = *(const bf16x8*)(whf + bo + 32);
        bf16x8 bl0 = *(const bf16x8*)(wlf + bo);
        bf16x8 bl1 = *(const bf16x8*)(wlf + bo + 32);
        const float nw2 = nw2s[col];
#pragma unroll
        for (int mt = 0; mt < 4; ++mt) {
            f32x4 c = {nw2, nw2, nw2, nw2};
            c = __builtin_amdgcn_mfma_f32_16x16x32_bf16(ah[mt][0], bh0, c, 0, 0, 0);
            c = __builtin_amdgcn_mfma_f32_16x16x32_bf16(ah[mt][1], bh1, c, 0, 0, 0);
            c = __builtin_amdgcn_mfma_f32_16x16x32_bf16(ah[mt][0], bl0, c, 0, 0, 0);
            c = __builtin_amdgcn_mfma_f32_16x16x32_bf16(ah[mt][1], bl1, c, 0, 0, 0);
            c = __builtin_amdgcn_mfma_f32_16x16x32_bf16(al[mt][0], bh0, c, 0, 0, 0);
            c = __builtin_amdgcn_mfma_f32_16x16x32_bf16(al[mt][1], bh1, c, 0, 0, 0);
#pragma unroll
            for (int r = 0; r < 4; ++r) {
                const int ri = mt * 4 + r;
                const float sc = -c[r];                    // folds into mods
                const bool lt = sc < m1[ri];               // strict: first idx
                m2[ri]  = __builtin_amdgcn_fmed3f(sc, m1[ri], m2[ri]);
                m1[ri]  = lt ? sc : m1[ri];
                idx[ri] = lt ? col : idx[ri];
            }
        }
    }

    // ---- intra-wave merge: top-2 across the 16 lc-lanes holding each row ----
#pragma unroll
    for (int ri = 0; ri < 16; ++ri) {
        float a1 = m1[ri], a2 = m2[ri];
        int ai = idx[ri];
#pragma unroll
        for (int off = 1; off < 16; off <<= 1) {
            const float b1 = __shfl_xor(a1, off, 64);
            const float b2 = __shfl_xor(a2, off, 64);
            const int   bi = __shfl_xor(ai, off, 64);
            const float hi = fmaxf(a1, b1);
            const bool take = (b1 < a1) || (b1 == a1 && bi < ai);
            a1 = take ? b1 : a1;
            ai = take ? bi : ai;
            a2 = fminf(fminf(a2, b2), hi);
        }
        m1[ri] = a1; m2[ri] = a2; idx[ri] = ai;
    }

    // lanes lc==0 publish per-row quarter results
    if (lc == 0) {
#pragma unroll
        for (int ri = 0; ri < 16; ++ri) {
            const int mt = ri >> 2, r = ri & 3;
            const int row = mt * 16 + kq * 4 + r;
            mrg1[wave][row] = m1[ri];
            mrg2[wave][row] = m2[ri];
            mrgi[wave][row] = idx[ri];
        }
    }
    __syncthreads();

    // ---- cross-wave merge (quarters in ascending col order -> strict <
    // keeps lowest col on ties) + keys/flags write. 64 lanes = 64 rows.
    if (tid < 64) {
        const int row = tid;
        float a1 = mrg1[0][row], a2 = mrg2[0][row];
        int ai = mrgi[0][row];
#pragma unroll
        for (int wq = 1; wq < 4; ++wq) {
            const float b1 = mrg1[wq][row];
            const float b2 = mrg2[wq][row];
            const int   bi = mrgi[wq][row];
            const float hi = fmaxf(a1, b1);
            const bool take = b1 < a1;     // b's cols all higher: ties keep a
            a2 = fminf(fminf(a2, b2), hi);
            a1 = take ? b1 : a1;
            ai = take ? bi : ai;
        }
        const int g = f * NN + n0 + row;
        keys[g]  = (unsigned int)ai;
        flags[g] = (a2 - a1 < TAU) ? 1 : 0;
    }
}

// ---------------------------------------------------------------------------
// rescue: exact fp32 full-K argmin for flagged rows. One wave per 64-row
// group: ballot the flags, full-wave rescan per set row. No atomics.
// ---------------------------------------------------------------------------
__global__ __launch_bounds__(256)
void vq_rescue(const float* __restrict__ x_in, const float* __restrict__ wt,
               const float* __restrict__ w2h,
               const unsigned char* __restrict__ flags,
               unsigned int* __restrict__ keys) {
    const int lane = threadIdx.x & 63;
    const int wid  = (blockIdx.x * 256 + threadIdx.x) >> 6;  // [0, 2048)
    const int base = wid * 64;

    unsigned long long m = __ballot(flags[base + lane] != 0);
    while (m) {
        const int r = __ffsll(m) - 1;
        m &= m - 1;
        const int g = base + r;
        const int f = g >> 12;                               // / NN
        const float* __restrict__ xr  = x_in + (size_t)g * ND;
        const float* __restrict__ wtf = wt + (size_t)f * NK * ND;
        unsigned long long best = 0xFFFFFFFFFFFFFFFFULL;
#pragma unroll 1
        for (int jj = 0; jj < 8; ++jj) {
            const int col = jj * 64 + lane;
            const float* __restrict__ wr = wtf + (size_t)col * ND;
            float t = w2h[f * NK + col];
#pragma unroll
            for (int d = 0; d < ND; d += 4) {
                float4 xv = *(const float4*)(xr + d);   // broadcast
                float4 wv = *(const float4*)(wr + d);
                t = fmaf(-xv.x, wv.x, t);
                t = fmaf(-xv.y, wv.y, t);
                t = fmaf(-xv.z, wv.z, t);
                t = fmaf(-xv.w, wv.w, t);
            }
            unsigned int u = __float_as_uint(t);
            u ^= (unsigned int)((int)u >> 31) | 0x80000000u;
            const unsigned long long key =
                ((unsigned long long)u << 32) | (unsigned int)col;
            best = key < best ? key : best;
        }
#pragma unroll
        for (int off = 32; off > 0; off >>= 1) {
            const unsigned long long o = __shfl_xor(best, off, 64);
            best = o < best ? o : best;
        }
        if (lane == 0) keys[g] = (unsigned int)(best & 0xFFFFFFFFULL);
    }
}

// ---------------------------------------------------------------------------
// gather: 4 threads per row; straight-through output. Per-block loss partial
// (plain store, no atomics). 2048 blocks.
// ---------------------------------------------------------------------------
__global__ __launch_bounds__(256)
void vq_gather(const float* __restrict__ x_in, const float* __restrict__ wt,
               const unsigned int* __restrict__ keys, float* __restrict__ out,
               float* __restrict__ partial) {
    const int gid = blockIdx.x * 256 + threadIdx.x;   // [0, NF*NN*4)
    const int row = gid >> 2;
    const int c   = (gid & 3) * 16;
    const int f   = row >> 12;
    const unsigned int k = keys[row];

    const float* __restrict__ q16 = wt + ((size_t)f * NK + k) * ND + c;
    const float* __restrict__ x16 = x_in + (size_t)row * ND + c;
    float* __restrict__ o16       = out + (size_t)row * ND + c;

    float lsum = 0.0f;
#pragma unroll
    for (int jj = 0; jj < 4; ++jj) {
        float4 qv = *(const float4*)(q16 + 4 * jj);
        float4 xv = *(const float4*)(x16 + 4 * jj);
        const float dx0 = qv.x - xv.x;
        const float dx1 = qv.y - xv.y;
        const float dx2 = qv.z - xv.z;
        const float dx3 = qv.w - xv.w;
        lsum = fmaf(dx0, dx0, lsum);
        lsum = fmaf(dx1, dx1, lsum);
        lsum = fmaf(dx2, dx2, lsum);
        lsum = fmaf(dx3, dx3, lsum);
        *(float4*)(o16 + 4 * jj) = qv;
    }

#pragma unroll
    for (int off = 32; off > 0; off >>= 1) {
        lsum += __shfl_down(lsum, off, 64);
    }
    __shared__ float wsum[4];
    if ((threadIdx.x & 63) == 0) wsum[threadIdx.x >> 6] = lsum;
    __syncthreads();
    if (threadIdx.x == 0) {
        partial[blockIdx.x] = wsum[0] + wsum[1] + wsum[2] + wsum[3];
    }
}

// ---------------------------------------------------------------------------
// loss_final: sum 2048 partials -> loss scalar. 1 block.
// ---------------------------------------------------------------------------
__global__ __launch_bounds__(256)
void vq_loss_final(const float* __restrict__ partial, float* __restrict__ loss) {
    float s = 0.0f;
    for (int i = threadIdx.x; i < NPARTIAL; i += 256) s += partial[i];
#pragma unroll
    for (int off = 32; off > 0; off >>= 1) s += __shfl_down(s, off, 64);
    __shared__ float wsum[4];
    if ((threadIdx.x & 63) == 0) wsum[threadIdx.x >> 6] = s;
    __syncthreads();
    if (threadIdx.x == 0) {
        *loss = (wsum[0] + wsum[1] + wsum[2] + wsum[3]) * LOSS_SCALE;
    }
}

extern "C" void kernel_launch(void* const* d_in, const int* in_sizes, int n_in,
                              void* d_out, int out_size, void* d_ws, size_t ws_size,
                              hipStream_t stream) {
    const float* x_in = (const float*)d_in[0];  // [F, N, D] fp32
    const float* w    = (const float*)d_in[1];  // [F, D, K] fp32
    float* out        = (float*)d_out;          // [F*N*D] output then [1] loss

    float* wt  = (float*)d_ws;                                   // 4 MB
    float* w2h = wt + (size_t)NF * NK * ND;                      // 64 KB
    unsigned short* wh = (unsigned short*)(w2h + NF * NK);       // 2 MB
    unsigned short* wl = wh + (size_t)NF * NK * ND;              // 2 MB
    unsigned int* keys = (unsigned int*)(wl + (size_t)NF * NK * ND); // 512 KB
    unsigned char* flags = (unsigned char*)(keys + (size_t)NF * NN); // 128 KB
    float* partial = (float*)(flags + (size_t)NF * NN);          // 8 KB

    float* loss_slot = out + (size_t)NF * NN * ND;

    vq_prep_w<<<NF * NK * 8 / 256, 256, 0, stream>>>(w, wt, wh, wl, w2h);

    vq_argmin<<<NF * NN / 64, 256, 0, stream>>>(x_in, wh, wl, w2h, keys, flags);

    vq_rescue<<<NF * NN / 64 / 4, 256, 0, stream>>>(x_in, wt, w2h, flags, keys);

    vq_gather<<<NF * NN * 4 / 256, 256, 0, stream>>>(x_in, wt, keys, out, partial);

    vq_loss_final<<<1, 256, 0, stream>>>(partial, loss_slot);
}

// Round 11
// 187.204 us; speedup vs baseline: 1.0585x; 1.0585x over previous
//
#include <hip/hip_runtime.h>
#include <math.h>

#define NF 32
#define NN 4096
#define ND 64
#define NK 512

// loss = q_latent + 0.25 * e_latent = 1.25 * mean((q - x)^2)
#define LOSS_SCALE (1.25f / (float)(NF * NN * ND))
// rescue margin: rows with approx top-2 gap < TAU get exact fp32 re-argmin.
// error budget: split-bf16 ~1.2e-4 + col-packing (<=512 ulp @ |s|<=8) ~5e-4
// -> 1.5e-3 gives ~2x margin.
#define TAU 1.5e-3f

#define NPARTIAL (NF * NN * 4 / 256)   // 2048 gather blocks

typedef short bf16x8 __attribute__((ext_vector_type(8)));
typedef float f32x4 __attribute__((ext_vector_type(4)));

static __device__ __forceinline__ unsigned short f2bf_rne(float f) {
    unsigned int u = __float_as_uint(f);
    u += 0x7FFFu + ((u >> 16) & 1u);
    return (unsigned short)(u >> 16);
}
static __device__ __forceinline__ float bf2f(unsigned short h) {
    return __uint_as_float(((unsigned int)h) << 16);
}

// async global->LDS: 16B per lane, dest = wave-uniform base + lane*16
static __device__ __forceinline__ void gload_lds16(const void* g, void* l) {
    __builtin_amdgcn_global_load_lds(
        (const __attribute__((address_space(1))) unsigned int*)g,
        (__attribute__((address_space(3))) unsigned int*)l, 16, 0, 0);
}

// ---------------------------------------------------------------------------
// prep_w (fused): wt[f][k][d] = w[f][d][k]; wh/wl bf16 split; w2h = 0.5||w||^2
// via 8-lane shuffle reduce. thread per (f,k,dc): 512 blocks.
// ---------------------------------------------------------------------------
__global__ __launch_bounds__(256)
void vq_prep_w(const float* __restrict__ w, float* __restrict__ wt,
               unsigned short* __restrict__ wh, unsigned short* __restrict__ wl,
               float* __restrict__ w2h) {
    const int gid = blockIdx.x * 256 + threadIdx.x;   // [0, NF*NK*8)
    const int dc = gid & 7;
    const int k  = (gid >> 3) & (NK - 1);
    const int f  = gid >> 12;
    const float* __restrict__ wf = w + (size_t)f * ND * NK;
    const size_t rowo = ((size_t)f * NK + k) * ND + dc * 8;

    float v[8];
    unsigned short hh[8], ll[8];
    float s = 0.0f;
#pragma unroll
    for (int j = 0; j < 8; ++j) {
        v[j] = wf[(dc * 8 + j) * NK + k];
        s = fmaf(v[j], v[j], s);
        hh[j] = f2bf_rne(v[j]);
        ll[j] = f2bf_rne(v[j] - bf2f(hh[j]));
    }
    *(float4*)(wt + rowo)     = make_float4(v[0], v[1], v[2], v[3]);
    *(float4*)(wt + rowo + 4) = make_float4(v[4], v[5], v[6], v[7]);
    *(ushort4*)(wh + rowo)     = make_ushort4(hh[0], hh[1], hh[2], hh[3]);
    *(ushort4*)(wh + rowo + 4) = make_ushort4(hh[4], hh[5], hh[6], hh[7]);
    *(ushort4*)(wl + rowo)     = make_ushort4(ll[0], ll[1], ll[2], ll[3]);
    *(ushort4*)(wl + rowo + 4) = make_ushort4(ll[4], ll[5], ll[6], ll[7]);

    s += __shfl_xor(s, 1, 64);
    s += __shfl_xor(s, 2, 64);
    s += __shfl_xor(s, 4, 64);
    if (dc == 0) w2h[f * NK + k] = 0.5f * s;
}

// ---------------------------------------------------------------------------
// argmin: block = 4 waves x 32 rows = 128 rows, all K=512 cols. R8 structure
// (async-LDS dbuf staging, one barrier per supertile) with:
//  - 32-col supertiles: LDS 18KB -> 6-8 blocks/CU (R8's 34KB capped at 4;
//    barrier stalls now hidden by co-resident blocks)
//  - A holds NEGATED x split -> MFMA acc (init +0.5||w||^2) IS the score
//  - packed-float top-2: score low 9 mantissa bits replaced by col; no idx
//    regs, min/med3-only tail, 2-shuffle merge. col-order skew for negative
//    scores + packing error are covered by TAU (exact rescue fixes both).
// grid: 1024 blocks, XCD-swizzled (f's B-data stays hot in one XCD L2).
// ---------------------------------------------------------------------------
__global__ __launch_bounds__(256, 4)
void vq_argmin(const float* __restrict__ x_in,
               const unsigned short* __restrict__ wh,
               const unsigned short* __restrict__ wl,
               const float* __restrict__ w2h,
               unsigned int* __restrict__ keys,
               unsigned char* __restrict__ flags) {
    const int b    = blockIdx.x;          // [0, 1024)
    const int j    = b >> 3;              // [0, 128)
    const int f    = (b & 7) * 4 + (j & 3);
    const int xt   = j >> 2;              // [0, 32)
    const int tid  = threadIdx.x;
    const int wave = tid >> 6;
    const int lane = tid & 63;
    const int lc   = lane & 15;
    const int q    = lane >> 4;
    const int n0   = xt * 128 + wave * 32;   // wave's private 32 rows

    __shared__ float w2s[NK];                             // 2 KB
    __shared__ __align__(16) unsigned short bstage[2][4096];  // 2 x 8 KB

    for (int t = tid; t < NK; t += 256) w2s[t] = w2h[f * NK + t];

    // ---- A-frags: 32 rows' (-x), split to bf16 hi/lo in-register.
    // A[m = lane&15][k = q*8 + j]; mt selects rows n0 + mt*16 + lc.
    bf16x8 ah[2][2], al[2][2];
    const float* __restrict__ xbase = x_in + ((size_t)f * NN + n0 + lc) * ND;
#pragma unroll
    for (int mt = 0; mt < 2; ++mt) {
#pragma unroll
        for (int s = 0; s < 2; ++s) {
            const float* p = xbase + mt * 16 * ND + s * 32 + q * 8;
            float4 u0 = *(const float4*)(p);
            float4 u1 = *(const float4*)(p + 4);
            float xv[8] = {-u0.x, -u0.y, -u0.z, -u0.w, -u1.x, -u1.y, -u1.z, -u1.w};
            bf16x8 h, l;
#pragma unroll
            for (int jj = 0; jj < 8; ++jj) {
                unsigned short hb = f2bf_rne(xv[jj]);
                unsigned short lb = f2bf_rne(xv[jj] - bf2f(hb));
                h[jj] = (short)hb;
                l[jj] = (short)lb;
            }
            ah[mt][s] = h;
            al[mt][s] = l;
        }
    }

    const unsigned short* __restrict__ whf = wh + (size_t)f * NK * ND;
    const unsigned short* __restrict__ wlf = wl + (size_t)f * NK * ND;

    float m1[8], m2[8];
#pragma unroll
    for (int ri = 0; ri < 8; ++ri) { m1[ri] = INFINITY; m2[ri] = INFINITY; }

    // ---- stage supertile st (32 cols) into bstage[pb]: 8 chunks of 1KB,
    // 2 per wave. chunk c = tl*4 + sg*2 + a (tl: 16-col tile, sg: kstep,
    // a: h/l). lane-linear dest (global_load_lds constraint).
#define STAGE(st, pb) do {                                                  \
    _Pragma("unroll")                                                       \
    for (int rep = 0; rep < 2; ++rep) {                                     \
        const int c  = wave * 2 + rep;                                      \
        const int tl = c >> 2;                                              \
        const int sg = (c >> 1) & 1;                                        \
        const unsigned short* src = ((c & 1) ? wlf : whf) +                 \
            (size_t)((st) * 32 + tl * 16 + lc) * ND + q * 8 + sg * 32;      \
        gload_lds16(src, &bstage[pb][c * 512]);                             \
    }                                                                       \
} while (0)

    STAGE(0, 0);

    for (int st = 0; st < 16; ++st) {
        __syncthreads();                 // drains this st's loads (vmcnt)
        if (st < 15) STAGE(st + 1, (st + 1) & 1);
        const unsigned short* __restrict__ bb = &bstage[st & 1][0];

#pragma unroll
        for (int tl = 0; tl < 2; ++tl) {
            const int col = st * 32 + tl * 16 + lc;
            bf16x8 bh0 = *(const bf16x8*)(bb + (tl * 4 + 0) * 512 + lane * 8);
            bf16x8 bl0 = *(const bf16x8*)(bb + (tl * 4 + 1) * 512 + lane * 8);
            bf16x8 bh1 = *(const bf16x8*)(bb + (tl * 4 + 2) * 512 + lane * 8);
            bf16x8 bl1 = *(const bf16x8*)(bb + (tl * 4 + 3) * 512 + lane * 8);
            const float w2 = w2s[col];
#pragma unroll
            for (int mt = 0; mt < 2; ++mt) {
                f32x4 c = {w2, w2, w2, w2};
                c = __builtin_amdgcn_mfma_f32_16x16x32_bf16(ah[mt][0], bh0, c, 0, 0, 0);
                c = __builtin_amdgcn_mfma_f32_16x16x32_bf16(ah[mt][1], bh1, c, 0, 0, 0);
                c = __builtin_amdgcn_mfma_f32_16x16x32_bf16(ah[mt][0], bl0, c, 0, 0, 0);
                c = __builtin_amdgcn_mfma_f32_16x16x32_bf16(ah[mt][1], bl1, c, 0, 0, 0);
                c = __builtin_amdgcn_mfma_f32_16x16x32_bf16(al[mt][0], bh0, c, 0, 0, 0);
                c = __builtin_amdgcn_mfma_f32_16x16x32_bf16(al[mt][1], bh1, c, 0, 0, 0);
#pragma unroll
                for (int r = 0; r < 4; ++r) {
                    const int ri = mt * 4 + r;
                    // pack col into low 9 mantissa bits (score IS c[r])
                    const float key = __uint_as_float(
                        (__float_as_uint(c[r]) & 0xFFFFFE00u) | (unsigned int)col);
                    m2[ri] = __builtin_amdgcn_fmed3f(key, m1[ri], m2[ri]);
                    m1[ri] = fminf(key, m1[ri]);
                }
            }
        }
    }

    // ---- merge top-2 across the 16 lanes holding each row ----
#pragma unroll
    for (int ri = 0; ri < 8; ++ri) {
        float a1 = m1[ri], a2 = m2[ri];
#pragma unroll
        for (int off = 1; off < 16; off <<= 1) {
            const float b1 = __shfl_xor(a1, off, 64);
            const float b2 = __shfl_xor(a2, off, 64);
            a2 = fminf(fminf(a2, b2), fmaxf(a1, b1));
            a1 = fminf(a1, b1);
        }
        m1[ri] = a1; m2[ri] = a2;
    }

    if (lc == 0) {
#pragma unroll
        for (int mt = 0; mt < 2; ++mt) {
            const int g = f * NN + n0 + mt * 16 + q * 4;   // 4 consecutive rows
            uint4 kv;
            uchar4 fl;
#pragma unroll
            for (int r = 0; r < 4; ++r) {
                const int ri = mt * 4 + r;
                const unsigned int u1 = __float_as_uint(m1[ri]);
                const unsigned int u2 = __float_as_uint(m2[ri]);
                const float s1 = __uint_as_float(u1 & 0xFFFFFE00u);
                const float s2 = __uint_as_float(u2 & 0xFFFFFE00u);
                ((unsigned int*)&kv)[r] = u1 & 0x1FFu;
                ((unsigned char*)&fl)[r] = (s2 - s1 < TAU) ? 1 : 0;
            }
            *(uint4*)(keys + g) = kv;
            *(uchar4*)(flags + g) = fl;
        }
    }
}

// ---------------------------------------------------------------------------
// rescue: exact fp32 full-K argmin for flagged rows. One wave per 64-row
// group: ballot the flags, full-wave rescan per set row. No atomics.
// ---------------------------------------------------------------------------
__global__ __launch_bounds__(256)
void vq_rescue(const float* __restrict__ x_in, const float* __restrict__ wt,
               const float* __restrict__ w2h,
               const unsigned char* __restrict__ flags,
               unsigned int* __restrict__ keys) {
    const int lane = threadIdx.x & 63;
    const int wid  = (blockIdx.x * 256 + threadIdx.x) >> 6;  // [0, 2048)
    const int base = wid * 64;

    unsigned long long m = __ballot(flags[base + lane] != 0);
    while (m) {
        const int r = __ffsll(m) - 1;
        m &= m - 1;
        const int g = base + r;
        const int f = g >> 12;                               // / NN
        const float* __restrict__ xr  = x_in + (size_t)g * ND;
        const float* __restrict__ wtf = wt + (size_t)f * NK * ND;
        unsigned long long best = 0xFFFFFFFFFFFFFFFFULL;
#pragma unroll 1
        for (int jj = 0; jj < 8; ++jj) {
            const int col = jj * 64 + lane;
            const float* __restrict__ wr = wtf + (size_t)col * ND;
            float t = w2h[f * NK + col];
#pragma unroll
            for (int d = 0; d < ND; d += 4) {
                float4 xv = *(const float4*)(xr + d);   // broadcast
                float4 wv = *(const float4*)(wr + d);
                t = fmaf(-xv.x, wv.x, t);
                t = fmaf(-xv.y, wv.y, t);
                t = fmaf(-xv.z, wv.z, t);
                t = fmaf(-xv.w, wv.w, t);
            }
            unsigned int u = __float_as_uint(t);
            u ^= (unsigned int)((int)u >> 31) | 0x80000000u;
            const unsigned long long key =
                ((unsigned long long)u << 32) | (unsigned int)col;
            best = key < best ? key : best;
        }
#pragma unroll
        for (int off = 32; off > 0; off >>= 1) {
            const unsigned long long o = __shfl_xor(best, off, 64);
            best = o < best ? o : best;
        }
        if (lane == 0) keys[g] = (unsigned int)(best & 0xFFFFFFFFULL);
    }
}

// ---------------------------------------------------------------------------
// gather: 4 threads per row; straight-through output. Per-block loss partial
// (plain store, no atomics). 2048 blocks.
// ---------------------------------------------------------------------------
__global__ __launch_bounds__(256)
void vq_gather(const float* __restrict__ x_in, const float* __restrict__ wt,
               const unsigned int* __restrict__ keys, float* __restrict__ out,
               float* __restrict__ partial) {
    const int gid = blockIdx.x * 256 + threadIdx.x;   // [0, NF*NN*4)
    const int row = gid >> 2;
    const int c   = (gid & 3) * 16;
    const int f   = row >> 12;
    const unsigned int k = keys[row];

    const float* __restrict__ q16 = wt + ((size_t)f * NK + k) * ND + c;
    const float* __restrict__ x16 = x_in + (size_t)row * ND + c;
    float* __restrict__ o16       = out + (size_t)row * ND + c;

    float lsum = 0.0f;
#pragma unroll
    for (int jj = 0; jj < 4; ++jj) {
        float4 qv = *(const float4*)(q16 + 4 * jj);
        float4 xv = *(const float4*)(x16 + 4 * jj);
        const float dx0 = qv.x - xv.x;
        const float dx1 = qv.y - xv.y;
        const float dx2 = qv.z - xv.z;
        const float dx3 = qv.w - xv.w;
        lsum = fmaf(dx0, dx0, lsum);
        lsum = fmaf(dx1, dx1, lsum);
        lsum = fmaf(dx2, dx2, lsum);
        lsum = fmaf(dx3, dx3, lsum);
        *(float4*)(o16 + 4 * jj) = qv;
    }

#pragma unroll
    for (int off = 32; off > 0; off >>= 1) {
        lsum += __shfl_down(lsum, off, 64);
    }
    __shared__ float wsum[4];
    if ((threadIdx.x & 63) == 0) wsum[threadIdx.x >> 6] = lsum;
    __syncthreads();
    if (threadIdx.x == 0) {
        partial[blockIdx.x] = wsum[0] + wsum[1] + wsum[2] + wsum[3];
    }
}

// ---------------------------------------------------------------------------
// loss_final: sum 2048 partials -> loss scalar. 1 block.
// ---------------------------------------------------------------------------
__global__ __launch_bounds__(256)
void vq_loss_final(const float* __restrict__ partial, float* __restrict__ loss) {
    float s = 0.0f;
    for (int i = threadIdx.x; i < NPARTIAL; i += 256) s += partial[i];
#pragma unroll
    for (int off = 32; off > 0; off >>= 1) s += __shfl_down(s, off, 64);
    __shared__ float wsum[4];
    if ((threadIdx.x & 63) == 0) wsum[threadIdx.x >> 6] = s;
    __syncthreads();
    if (threadIdx.x == 0) {
        *loss = (wsum[0] + wsum[1] + wsum[2] + wsum[3]) * LOSS_SCALE;
    }
}

extern "C" void kernel_launch(void* const* d_in, const int* in_sizes, int n_in,
                              void* d_out, int out_size, void* d_ws, size_t ws_size,
                              hipStream_t stream) {
    const float* x_in = (const float*)d_in[0];  // [F, N, D] fp32
    const float* w    = (const float*)d_in[1];  // [F, D, K] fp32
    float* out        = (float*)d_out;          // [F*N*D] output then [1] loss

    float* wt  = (float*)d_ws;                                   // 4 MB
    float* w2h = wt + (size_t)NF * NK * ND;                      // 64 KB
    unsigned short* wh = (unsigned short*)(w2h + NF * NK);       // 2 MB
    unsigned short* wl = wh + (size_t)NF * NK * ND;              // 2 MB
    unsigned int* keys = (unsigned int*)(wl + (size_t)NF * NK * ND); // 512 KB
    unsigned char* flags = (unsigned char*)(keys + (size_t)NF * NN); // 128 KB
    float* partial = (float*)(flags + (size_t)NF * NN);          // 8 KB

    float* loss_slot = out + (size_t)NF * NN * ND;

    vq_prep_w<<<NF * NK * 8 / 256, 256, 0, stream>>>(w, wt, wh, wl, w2h);

    vq_argmin<<<NF * NN / 128, 256, 0, stream>>>(x_in, wh, wl, w2h, keys, flags);

    vq_rescue<<<NF * NN / 64 / 4, 256, 0, stream>>>(x_in, wt, w2h, flags, keys);

    vq_gather<<<NF * NN * 4 / 256, 256, 0, stream>>>(x_in, wt, keys, out, partial);

    vq_loss_final<<<1, 256, 0, stream>>>(partial, loss_slot);
}

// Round 12
// 163.509 us; speedup vs baseline: 1.2119x; 1.1449x over previous
//
#include <hip/hip_runtime.h>
#include <math.h>

#define NF 32
#define NN 4096
#define ND 64
#define NK 512

// loss = q_latent + 0.25 * e_latent = 1.25 * mean((q - x)^2)
#define LOSS_SCALE (1.25f / (float)(NF * NN * ND))
// rescue margin: rows with approx top-2 gap < TAU get exact fp32 re-argmin.
// 4-term split-bf16 score error e_a ~ 3e-5 (fp32 accum only); col-pack trunc
// e_t ~ 6e-5. Safety bound 4*e_a + 2*e_t ~ 2.4e-4 -> TAU = 3e-4.
#define TAU 3e-4f

#define NPARTIAL (NF * NN * 4 / 256)   // 2048 gather blocks

typedef short bf16x8 __attribute__((ext_vector_type(8)));
typedef float f32x4 __attribute__((ext_vector_type(4)));

static __device__ __forceinline__ unsigned short f2bf_rne(float f) {
    unsigned int u = __float_as_uint(f);
    u += 0x7FFFu + ((u >> 16) & 1u);
    return (unsigned short)(u >> 16);
}
static __device__ __forceinline__ float bf2f(unsigned short h) {
    return __uint_as_float(((unsigned int)h) << 16);
}

// async global->LDS: 16B per lane, dest = wave-uniform base + lane*16
static __device__ __forceinline__ void gload_lds16(const void* g, void* l) {
    __builtin_amdgcn_global_load_lds(
        (const __attribute__((address_space(1))) unsigned int*)g,
        (__attribute__((address_space(3))) unsigned int*)l, 16, 0, 0);
}

// ---------------------------------------------------------------------------
// prep_w (fused): wt[f][k][d] = w[f][d][k]; wh/wl bf16 split; w2h = 0.5||w||^2
// via 8-lane shuffle reduce. thread per (f,k,dc): 512 blocks.
// ---------------------------------------------------------------------------
__global__ __launch_bounds__(256)
void vq_prep_w(const float* __restrict__ w, float* __restrict__ wt,
               unsigned short* __restrict__ wh, unsigned short* __restrict__ wl,
               float* __restrict__ w2h) {
    const int gid = blockIdx.x * 256 + threadIdx.x;   // [0, NF*NK*8)
    const int dc = gid & 7;
    const int k  = (gid >> 3) & (NK - 1);
    const int f  = gid >> 12;
    const float* __restrict__ wf = w + (size_t)f * ND * NK;
    const size_t rowo = ((size_t)f * NK + k) * ND + dc * 8;

    float v[8];
    unsigned short hh[8], ll[8];
    float s = 0.0f;
#pragma unroll
    for (int j = 0; j < 8; ++j) {
        v[j] = wf[(dc * 8 + j) * NK + k];
        s = fmaf(v[j], v[j], s);
        hh[j] = f2bf_rne(v[j]);
        ll[j] = f2bf_rne(v[j] - bf2f(hh[j]));
    }
    *(float4*)(wt + rowo)     = make_float4(v[0], v[1], v[2], v[3]);
    *(float4*)(wt + rowo + 4) = make_float4(v[4], v[5], v[6], v[7]);
    *(ushort4*)(wh + rowo)     = make_ushort4(hh[0], hh[1], hh[2], hh[3]);
    *(ushort4*)(wh + rowo + 4) = make_ushort4(hh[4], hh[5], hh[6], hh[7]);
    *(ushort4*)(wl + rowo)     = make_ushort4(ll[0], ll[1], ll[2], ll[3]);
    *(ushort4*)(wl + rowo + 4) = make_ushort4(ll[4], ll[5], ll[6], ll[7]);

    s += __shfl_xor(s, 1, 64);
    s += __shfl_xor(s, 2, 64);
    s += __shfl_xor(s, 4, 64);
    if (dc == 0) w2h[f * NK + k] = 0.5f * s;
}

// ---------------------------------------------------------------------------
// argmin: block = 4 waves x 32 rows = 128 rows, all K=512 cols. R11 structure
// (32-col async-LDS dbuf supertiles, 6-8 blocks/CU) with:
//  - FULL 4-term split MFMA (xh*wh + xh*wl + xl*wh + xl*wl): score error
//    drops to fp32-accum noise -> TAU 1.5e-3 -> 3e-4 -> ~5x less rescue work
//    (R11 post-mortem: rescue cost is linear in TAU and was 60us)
//  - hybrid tail: packed kmin (idx, no cndmask) + EXACT m1/m2 (flag gap)
// A holds NEGATED x split; acc init +0.5||w_k||^2 -> c IS the score.
// grid: 1024 blocks, XCD-swizzled.
// ---------------------------------------------------------------------------
__global__ __launch_bounds__(256, 4)
void vq_argmin(const float* __restrict__ x_in,
               const unsigned short* __restrict__ wh,
               const unsigned short* __restrict__ wl,
               const float* __restrict__ w2h,
               unsigned int* __restrict__ keys,
               unsigned char* __restrict__ flags) {
    const int b    = blockIdx.x;          // [0, 1024)
    const int j    = b >> 3;              // [0, 128)
    const int f    = (b & 7) * 4 + (j & 3);
    const int xt   = j >> 2;              // [0, 32)
    const int tid  = threadIdx.x;
    const int wave = tid >> 6;
    const int lane = tid & 63;
    const int lc   = lane & 15;
    const int q    = lane >> 4;
    const int n0   = xt * 128 + wave * 32;   // wave's private 32 rows

    __shared__ float w2s[NK];                             // 2 KB
    __shared__ __align__(16) unsigned short bstage[2][4096];  // 2 x 8 KB

    for (int t = tid; t < NK; t += 256) w2s[t] = w2h[f * NK + t];

    // ---- A-frags: 32 rows' (-x), split to bf16 hi/lo in-register.
    bf16x8 ah[2][2], al[2][2];
    const float* __restrict__ xbase = x_in + ((size_t)f * NN + n0 + lc) * ND;
#pragma unroll
    for (int mt = 0; mt < 2; ++mt) {
#pragma unroll
        for (int s = 0; s < 2; ++s) {
            const float* p = xbase + mt * 16 * ND + s * 32 + q * 8;
            float4 u0 = *(const float4*)(p);
            float4 u1 = *(const float4*)(p + 4);
            float xv[8] = {-u0.x, -u0.y, -u0.z, -u0.w, -u1.x, -u1.y, -u1.z, -u1.w};
            bf16x8 h, l;
#pragma unroll
            for (int jj = 0; jj < 8; ++jj) {
                unsigned short hb = f2bf_rne(xv[jj]);
                unsigned short lb = f2bf_rne(xv[jj] - bf2f(hb));
                h[jj] = (short)hb;
                l[jj] = (short)lb;
            }
            ah[mt][s] = h;
            al[mt][s] = l;
        }
    }

    const unsigned short* __restrict__ whf = wh + (size_t)f * NK * ND;
    const unsigned short* __restrict__ wlf = wl + (size_t)f * NK * ND;

    float m1[8], m2[8], kmin[8];
#pragma unroll
    for (int ri = 0; ri < 8; ++ri) { m1[ri] = INFINITY; m2[ri] = INFINITY; kmin[ri] = INFINITY; }

    // ---- stage supertile st (32 cols) into bstage[pb]: 8 chunks of 1KB,
    // 2 per wave. chunk c = tl*4 + sg*2 + a. lane-linear dest.
#define STAGE(st, pb) do {                                                  \
    _Pragma("unroll")                                                       \
    for (int rep = 0; rep < 2; ++rep) {                                     \
        const int c  = wave * 2 + rep;                                      \
        const int tl = c >> 2;                                              \
        const int sg = (c >> 1) & 1;                                        \
        const unsigned short* src = ((c & 1) ? wlf : whf) +                 \
            (size_t)((st) * 32 + tl * 16 + lc) * ND + q * 8 + sg * 32;      \
        gload_lds16(src, &bstage[pb][c * 512]);                             \
    }                                                                       \
} while (0)

    STAGE(0, 0);

    for (int st = 0; st < 16; ++st) {
        __syncthreads();                 // drains this st's loads (vmcnt)
        if (st < 15) STAGE(st + 1, (st + 1) & 1);
        const unsigned short* __restrict__ bb = &bstage[st & 1][0];

#pragma unroll
        for (int tl = 0; tl < 2; ++tl) {
            const int col = st * 32 + tl * 16 + lc;
            bf16x8 bh0 = *(const bf16x8*)(bb + (tl * 4 + 0) * 512 + lane * 8);
            bf16x8 bl0 = *(const bf16x8*)(bb + (tl * 4 + 1) * 512 + lane * 8);
            bf16x8 bh1 = *(const bf16x8*)(bb + (tl * 4 + 2) * 512 + lane * 8);
            bf16x8 bl1 = *(const bf16x8*)(bb + (tl * 4 + 3) * 512 + lane * 8);
            const float w2 = w2s[col];
#pragma unroll
            for (int mt = 0; mt < 2; ++mt) {
                f32x4 c = {w2, w2, w2, w2};
                c = __builtin_amdgcn_mfma_f32_16x16x32_bf16(ah[mt][0], bh0, c, 0, 0, 0);
                c = __builtin_amdgcn_mfma_f32_16x16x32_bf16(ah[mt][1], bh1, c, 0, 0, 0);
                c = __builtin_amdgcn_mfma_f32_16x16x32_bf16(ah[mt][0], bl0, c, 0, 0, 0);
                c = __builtin_amdgcn_mfma_f32_16x16x32_bf16(ah[mt][1], bl1, c, 0, 0, 0);
                c = __builtin_amdgcn_mfma_f32_16x16x32_bf16(al[mt][0], bh0, c, 0, 0, 0);
                c = __builtin_amdgcn_mfma_f32_16x16x32_bf16(al[mt][1], bh1, c, 0, 0, 0);
                c = __builtin_amdgcn_mfma_f32_16x16x32_bf16(al[mt][0], bl0, c, 0, 0, 0);
                c = __builtin_amdgcn_mfma_f32_16x16x32_bf16(al[mt][1], bl1, c, 0, 0, 0);
#pragma unroll
                for (int r = 0; r < 4; ++r) {
                    const int ri = mt * 4 + r;
                    const float sc = c[r];
                    // idx channel: col packed into low 9 mantissa bits
                    const float key = __uint_as_float(
                        (__float_as_uint(sc) & 0xFFFFFE00u) | (unsigned int)col);
                    kmin[ri] = fminf(kmin[ri], key);
                    // flag channel: exact top-2
                    m2[ri] = __builtin_amdgcn_fmed3f(sc, m1[ri], m2[ri]);
                    m1[ri] = fminf(sc, m1[ri]);
                }
            }
        }
    }

    // ---- merge top-2 + kmin across the 16 lanes holding each row ----
#pragma unroll
    for (int ri = 0; ri < 8; ++ri) {
        float a1 = m1[ri], a2 = m2[ri], ak = kmin[ri];
#pragma unroll
        for (int off = 1; off < 16; off <<= 1) {
            const float b1 = __shfl_xor(a1, off, 64);
            const float b2 = __shfl_xor(a2, off, 64);
            const float bk = __shfl_xor(ak, off, 64);
            a2 = fminf(fminf(a2, b2), fmaxf(a1, b1));
            a1 = fminf(a1, b1);
            ak = fminf(ak, bk);
        }
        m1[ri] = a1; m2[ri] = a2; kmin[ri] = ak;
    }

    if (lc == 0) {
#pragma unroll
        for (int mt = 0; mt < 2; ++mt) {
            const int g = f * NN + n0 + mt * 16 + q * 4;   // 4 consecutive rows
            uint4 kv;
            uchar4 fl;
#pragma unroll
            for (int r = 0; r < 4; ++r) {
                const int ri = mt * 4 + r;
                ((unsigned int*)&kv)[r] = __float_as_uint(kmin[ri]) & 0x1FFu;
                ((unsigned char*)&fl)[r] = (m2[ri] - m1[ri] < TAU) ? 1 : 0;
            }
            *(uint4*)(keys + g) = kv;
            *(uchar4*)(flags + g) = fl;
        }
    }
}

// ---------------------------------------------------------------------------
// rescue: exact fp32 full-K argmin for flagged rows. One wave per 16-row
// group (8192 waves: fine-grained -> small Poisson straggler tail). Ballot
// the flags, full-wave rescan per set row. No atomics.
// grid: 2048 blocks.
// ---------------------------------------------------------------------------
__global__ __launch_bounds__(256)
void vq_rescue(const float* __restrict__ x_in, const float* __restrict__ wt,
               const float* __restrict__ w2h,
               const unsigned char* __restrict__ flags,
               unsigned int* __restrict__ keys) {
    const int lane = threadIdx.x & 63;
    const int wid  = (blockIdx.x * 256 + threadIdx.x) >> 6;  // [0, 8192)
    const int base = wid * 16;

    const unsigned char flv = flags[base + (lane & 15)];
    unsigned long long m = __ballot(flv != 0 && lane < 16);
    while (m) {
        const int r = __ffsll(m) - 1;
        m &= m - 1;
        const int g = base + r;
        const int f = g >> 12;                               // / NN
        const float* __restrict__ xr  = x_in + (size_t)g * ND;
        const float* __restrict__ wtf = wt + (size_t)f * NK * ND;
        unsigned long long best = 0xFFFFFFFFFFFFFFFFULL;
#pragma unroll 1
        for (int jj = 0; jj < 8; ++jj) {
            const int col = jj * 64 + lane;
            const float* __restrict__ wr = wtf + (size_t)col * ND;
            float t = w2h[f * NK + col];
#pragma unroll
            for (int d = 0; d < ND; d += 4) {
                float4 xv = *(const float4*)(xr + d);   // broadcast
                float4 wv = *(const float4*)(wr + d);
                t = fmaf(-xv.x, wv.x, t);
                t = fmaf(-xv.y, wv.y, t);
                t = fmaf(-xv.z, wv.z, t);
                t = fmaf(-xv.w, wv.w, t);
            }
            unsigned int u = __float_as_uint(t);
            u ^= (unsigned int)((int)u >> 31) | 0x80000000u;
            const unsigned long long key =
                ((unsigned long long)u << 32) | (unsigned int)col;
            best = key < best ? key : best;
        }
#pragma unroll
        for (int off = 32; off > 0; off >>= 1) {
            const unsigned long long o = __shfl_xor(best, off, 64);
            best = o < best ? o : best;
        }
        if (lane == 0) keys[g] = (unsigned int)(best & 0xFFFFFFFFULL);
    }
}

// ---------------------------------------------------------------------------
// gather: 4 threads per row; straight-through output. Per-block loss partial
// (plain store, no atomics). 2048 blocks.
// ---------------------------------------------------------------------------
__global__ __launch_bounds__(256)
void vq_gather(const float* __restrict__ x_in, const float* __restrict__ wt,
               const unsigned int* __restrict__ keys, float* __restrict__ out,
               float* __restrict__ partial) {
    const int gid = blockIdx.x * 256 + threadIdx.x;   // [0, NF*NN*4)
    const int row = gid >> 2;
    const int c   = (gid & 3) * 16;
    const int f   = row >> 12;
    const unsigned int k = keys[row];

    const float* __restrict__ q16 = wt + ((size_t)f * NK + k) * ND + c;
    const float* __restrict__ x16 = x_in + (size_t)row * ND + c;
    float* __restrict__ o16       = out + (size_t)row * ND + c;

    float lsum = 0.0f;
#pragma unroll
    for (int jj = 0; jj < 4; ++jj) {
        float4 qv = *(const float4*)(q16 + 4 * jj);
        float4 xv = *(const float4*)(x16 + 4 * jj);
        const float dx0 = qv.x - xv.x;
        const float dx1 = qv.y - xv.y;
        const float dx2 = qv.z - xv.z;
        const float dx3 = qv.w - xv.w;
        lsum = fmaf(dx0, dx0, lsum);
        lsum = fmaf(dx1, dx1, lsum);
        lsum = fmaf(dx2, dx2, lsum);
        lsum = fmaf(dx3, dx3, lsum);
        *(float4*)(o16 + 4 * jj) = qv;
    }

#pragma unroll
    for (int off = 32; off > 0; off >>= 1) {
        lsum += __shfl_down(lsum, off, 64);
    }
    __shared__ float wsum[4];
    if ((threadIdx.x & 63) == 0) wsum[threadIdx.x >> 6] = lsum;
    __syncthreads();
    if (threadIdx.x == 0) {
        partial[blockIdx.x] = wsum[0] + wsum[1] + wsum[2] + wsum[3];
    }
}

// ---------------------------------------------------------------------------
// loss_final: sum 2048 partials -> loss scalar. 1 block.
// ---------------------------------------------------------------------------
__global__ __launch_bounds__(256)
void vq_loss_final(const float* __restrict__ partial, float* __restrict__ loss) {
    float s = 0.0f;
    for (int i = threadIdx.x; i < NPARTIAL; i += 256) s += partial[i];
#pragma unroll
    for (int off = 32; off > 0; off >>= 1) s += __shfl_down(s, off, 64);
    __shared__ float wsum[4];
    if ((threadIdx.x & 63) == 0) wsum[threadIdx.x >> 6] = s;
    __syncthreads();
    if (threadIdx.x == 0) {
        *loss = (wsum[0] + wsum[1] + wsum[2] + wsum[3]) * LOSS_SCALE;
    }
}

extern "C" void kernel_launch(void* const* d_in, const int* in_sizes, int n_in,
                              void* d_out, int out_size, void* d_ws, size_t ws_size,
                              hipStream_t stream) {
    const float* x_in = (const float*)d_in[0];  // [F, N, D] fp32
    const float* w    = (const float*)d_in[1];  // [F, D, K] fp32
    float* out        = (float*)d_out;          // [F*N*D] output then [1] loss

    float* wt  = (float*)d_ws;                                   // 4 MB
    float* w2h = wt + (size_t)NF * NK * ND;                      // 64 KB
    unsigned short* wh = (unsigned short*)(w2h + NF * NK);       // 2 MB
    unsigned short* wl = wh + (size_t)NF * NK * ND;              // 2 MB
    unsigned int* keys = (unsigned int*)(wl + (size_t)NF * NK * ND); // 512 KB
    unsigned char* flags = (unsigned char*)(keys + (size_t)NF * NN); // 128 KB
    float* partial = (float*)(flags + (size_t)NF * NN);          // 8 KB

    float* loss_slot = out + (size_t)NF * NN * ND;

    vq_prep_w<<<NF * NK * 8 / 256, 256, 0, stream>>>(w, wt, wh, wl, w2h);

    vq_argmin<<<NF * NN / 128, 256, 0, stream>>>(x_in, wh, wl, w2h, keys, flags);

    vq_rescue<<<NF * NN / 16 / 4, 256, 0, stream>>>(x_in, wt, w2h, flags, keys);

    vq_gather<<<NF * NN * 4 / 256, 256, 0, stream>>>(x_in, wt, keys, out, partial);

    vq_loss_final<<<1, 256, 0, stream>>>(partial, loss_slot);
}